// Round 1
// baseline (627.433 us; speedup 1.0000x reference)
//
#include <hip/hip_runtime.h>
#include <hip/hip_bf16.h>

typedef float f4 __attribute__((ext_vector_type(4)));
typedef __bf16 bf16x4 __attribute__((ext_vector_type(4)));
typedef __bf16 bf16x8 __attribute__((ext_vector_type(8)));

#define BATCH 16
#define CCH 512
#define HW 4096

// async global->LDS, 16B per lane. LDS dest must be wave-uniform base (lane*16 implicit).
__device__ __forceinline__ void gld_lds16(const void* g, void* l) {
    __builtin_amdgcn_global_load_lds(
        (const __attribute__((address_space(1))) unsigned int*)g,
        (__attribute__((address_space(3))) unsigned int*)l, 16, 0, 0);
}

// ---------- fused stats + fp32->bf16 conversion for BOTH tensors (dst may be null) ----------
__global__ __launch_bounds__(256) void stats_conv_kernel(
    const float* __restrict__ fc, const float* __restrict__ fs,
    __bf16* __restrict__ fcb, __bf16* __restrict__ fsb,
    float* __restrict__ rstd_c, float* __restrict__ rmu_c,
    float* __restrict__ rstd_s, float* __restrict__ rmu_s)
{
    const int row = blockIdx.x;                    // B*C = 8192
    const float* pc = fc + (size_t)row * HW;
    const float* ps = fs + (size_t)row * HW;
    float sc = 0.f, qc = 0.f, ssum = 0.f, qs = 0.f;
    #pragma unroll
    for (int i0 = 0; i0 < HW / 8 / 256; i0++) {    // 2 iterations
        int i = i0 * 256 + threadIdx.x;
        f4 a0 = ((const f4*)pc)[2 * i], a1 = ((const f4*)pc)[2 * i + 1];
        f4 b0 = ((const f4*)ps)[2 * i], b1 = ((const f4*)ps)[2 * i + 1];
        #pragma unroll
        for (int t = 0; t < 4; t++) {
            sc += a0[t] + a1[t];
            qc = fmaf(a0[t], a0[t], fmaf(a1[t], a1[t], qc));
            ssum += b0[t] + b1[t];
            qs = fmaf(b0[t], b0[t], fmaf(b1[t], b1[t], qs));
        }
        if (fcb) {
            bf16x8 oa, ob;
            #pragma unroll
            for (int t = 0; t < 4; t++) {
                oa[t] = (__bf16)a0[t]; oa[4 + t] = (__bf16)a1[t];
                ob[t] = (__bf16)b0[t]; ob[4 + t] = (__bf16)b1[t];
            }
            *(bf16x8*)(fcb + (size_t)row * HW + i * 8) = oa;
            *(bf16x8*)(fsb + (size_t)row * HW + i * 8) = ob;
        }
    }
    for (int off = 32; off > 0; off >>= 1) {
        sc   += __shfl_down(sc,   off, 64);
        qc   += __shfl_down(qc,   off, 64);
        ssum += __shfl_down(ssum, off, 64);
        qs   += __shfl_down(qs,   off, 64);
    }
    __shared__ float red[4][4];
    if ((threadIdx.x & 63) == 0) {
        int w = threadIdx.x >> 6;
        red[w][0] = sc; red[w][1] = qc; red[w][2] = ssum; red[w][3] = qs;
    }
    __syncthreads();
    if (threadIdx.x == 0) {
        float Sc = red[0][0] + red[1][0] + red[2][0] + red[3][0];
        float Qc = red[0][1] + red[1][1] + red[2][1] + red[3][1];
        float Ss = red[0][2] + red[1][2] + red[2][2] + red[3][2];
        float Qs = red[0][3] + red[1][3] + red[2][3] + red[3][3];
        float muc = Sc * (1.f / HW), varc = Qc * (1.f / HW) - muc * muc;
        float mus = Ss * (1.f / HW), vars = Qs * (1.f / HW) - mus * mus;
        float rc = rsqrtf(varc + 1e-5f), rs = rsqrtf(vars + 1e-5f);
        rstd_c[row] = rc; rmu_c[row] = rc * muc;
        rstd_s[row] = rs; rmu_s[row] = rs * mus;
    }
}

// ---------- weight prep: w2 -> bf16; w1,w3 -> transposed bf16 ----------
__global__ __launch_bounds__(256) void prep_w_kernel(
    const float* __restrict__ w1, const float* __restrict__ w2, const float* __restrict__ w3,
    __bf16* __restrict__ w1t, __bf16* __restrict__ w2b, __bf16* __restrict__ w3t)
{
    int i = blockIdx.x * 256 + threadIdx.x;
    int z = blockIdx.y;
    if (z == 0)      w2b[i] = (__bf16)w2[i];
    else if (z == 1) w3t[i] = (__bf16)w3[(i & 511) * 512 + (i >> 9)];
    else             w1t[i] = (__bf16)w1[(i & 511) * 512 + (i >> 9)];
}

// ---------- u1[d] = sum_x w1[x,d]*b3[x] ; bw3[d] = sum_x w3[x,d]*b1[x] ----------
__global__ __launch_bounds__(256) void u_kernel(
    const float* __restrict__ w1, const float* __restrict__ b3,
    const float* __restrict__ w3, const float* __restrict__ b1,
    float* __restrict__ u1, float* __restrict__ bw3)
{
    int d = blockIdx.x * 256 + threadIdx.x;        // grid (2, 2)
    const float* W = blockIdx.y == 0 ? w1 : w3;
    const float* v = blockIdx.y == 0 ? b3 : b1;
    float* o       = blockIdx.y == 0 ? u1 : bw3;
    float s = 0.f;
    for (int x = 0; x < 512; x++) s += W[x * 512 + d] * v[x];
    o[d] = s;
}

__global__ __launch_bounds__(256) void b1b3_kernel(
    const float* __restrict__ b1, const float* __restrict__ b3, float* __restrict__ o)
{
    int t = threadIdx.x;
    float s = b1[t] * b3[t] + b1[t + 256] * b3[t + 256];
    for (int off = 32; off > 0; off >>= 1) s += __shfl_down(s, off, 64);
    __shared__ float ss[4];
    if ((t & 63) == 0) ss[t >> 6] = s;
    __syncthreads();
    if (t == 0) o[0] = ss[0] + ss[1] + ss[2] + ss[3];
}

// ---------- Gram epilogue: G = bf16( rs_s*rs_c*Graw - 4096*rmu_s*rmu_c ) ----------
__global__ __launch_bounds__(256) void gram_epi_kernel(
    const float* __restrict__ Graw, __bf16* __restrict__ G,
    const float* __restrict__ rstd_s, const float* __restrict__ rmu_s,
    const float* __restrict__ rstd_c, const float* __restrict__ rmu_c)
{
    size_t i4 = (size_t)blockIdx.x * 256 + threadIdx.x;
    size_t flat = i4 * 4;
    int b  = (int)(flat >> 18);
    int c  = (int)((flat >> 9) & 511);
    int d0 = (int)(flat & 511);
    float rs = rstd_s[b * 512 + c], rm = rmu_s[b * 512 + c];
    f4 g = *(const f4*)(Graw + flat);
    bf16x4 o;
    #pragma unroll
    for (int t = 0; t < 4; t++) {
        float val = rs * rstd_c[b * 512 + d0 + t] * g[t]
                  - 4096.f * rm * rmu_c[b * 512 + d0 + t];
        o[t] = (__bf16)val;
    }
    *(bf16x4*)(G + flat) = o;
}

// ---------- q[b,x] = sum_d G[b,x,d]*u1[d] ----------
__global__ __launch_bounds__(64) void q_kernel(
    const __bf16* __restrict__ G, const float* __restrict__ u1, float* __restrict__ q)
{
    int r = blockIdx.x;
    const __bf16* row = G + (size_t)r * 512;
    float s = 0.f;
    for (int i = threadIdx.x; i < 512; i += 64) s += (float)row[i] * u1[i];
    for (int off = 32; off > 0; off >>= 1) s += __shfl_down(s, off, 64);
    if (threadIdx.x == 0) q[r] = s;
}

// ---------- v[b,c] = sum_x w2[c,x]*q[b,x] + 4096*(b1.b3)*b2[c] ----------
__global__ __launch_bounds__(64) void v2_kernel(
    const float* __restrict__ w2, const float* __restrict__ qv,
    const float* __restrict__ b2, const float* __restrict__ b1b3,
    float* __restrict__ vv)
{
    int r = blockIdx.x, b = r >> 9, c = r & 511;
    float s = 0.f;
    for (int i = threadIdx.x; i < 512; i += 64) s += w2[c * 512 + i] * qv[b * 512 + i];
    for (int off = 32; off > 0; off >>= 1) s += __shfl_down(s, off, 64);
    if (threadIdx.x == 0) vv[r] = s + 4096.f * b1b3[0] * b2[c];
}

// ---------- bf16 transpose: out[b][n][e] = in[b][e][n]  (512 x 4096 -> 4096 x 512) ----------
__global__ __launch_bounds__(256) void transpose_kernel(
    const __bf16* __restrict__ in, __bf16* __restrict__ out)
{
    __shared__ __align__(16) __bf16 t[64 * 64];    // XOR slot-swizzled, pitch 64
    const int b = blockIdx.z, e0 = blockIdx.y * 64, n0 = blockIdx.x * 64;
    const int tid = threadIdx.x;
    const __bf16* src = in + ((size_t)b * 512 + e0) * HW + n0;
    __bf16* dst = out + ((size_t)b * HW + n0) * 512 + e0;
    #pragma unroll
    for (int it = 0; it < 2; it++) {
        int idx = it * 256 + tid;
        int e = idx >> 3, v = idx & 7;
        *(bf16x8*)&t[e * 64 + ((v ^ (e & 7)) * 8)] =
            *(const bf16x8*)(src + (size_t)e * HW + v * 8);
    }
    __syncthreads();
    #pragma unroll
    for (int it = 0; it < 2; it++) {
        int idx = it * 256 + tid;
        int n = idx >> 3, v = idx & 7;             // out row n, e-chunk v
        bf16x8 o;
        #pragma unroll
        for (int u = 0; u < 8; u++) {
            int row = v * 8 + u;                   // row&7 == u
            o[u] = t[row * 64 + (((n >> 3) ^ u) * 8) + (n & 7)];
        }
        *(bf16x8*)(dst + (size_t)n * 512 + v * 8) = o;
    }
}

// ---------- fast NT bf16 GEMM: global_load_lds staging, XOR-swizzled LDS ----------
// D[b][i][j] = sum_k A[b][i][k] * B[b][j][k]; BK=64, both operands K-major bf16.
// Epilogue: val = acc + tscale*t1[row]*t2[col] (t1/t2 nullable). ATOMIC: fp32 atomicAdd.
template<int BM, int BN, bool D_F32, bool ATOMIC>
__global__ __launch_bounds__(256) void gemm_nt_lds(
    const __bf16* __restrict__ A, const __bf16* __restrict__ B, void* __restrict__ D,
    int K, int splitk, int lda, int ldb, int ldd,
    long long sA, long long sB, long long sD,
    const float* __restrict__ t1, int vt1, const float* __restrict__ t2, int vt2,
    float tscale)
{
    constexpr int FM = BM / 32, FN = BN / 32;
    __shared__ __align__(16) __bf16 As[BM * 64];
    __shared__ __align__(16) __bf16 Bs[BN * 64];

    const int tid = threadIdx.x;
    const int lane = tid & 63, wid = tid >> 6;
    const int b = blockIdx.z / splitk, chunk = blockIdx.z % splitk;
    const int klen = K / splitk, k0 = chunk * klen, k1 = k0 + klen;
    const int m0 = blockIdx.y * BM, n0 = blockIdx.x * BN;
    const int l16 = lane & 15, l4 = lane >> 4;
    const int wm = (wid >> 1) * (BM / 2), wn = (wid & 1) * (BN / 2);
    // staging geometry: each 1024B chunk = 8 rows x 128B; 8 lanes/row, 16B/lane.
    const int r_in = lane >> 3, slot = lane & 7;
    const int csw = (slot ^ r_in) * 8;             // pre-swizzled source column (elements)
    const int rsw = (l16 & 7) * 8;                 // read-side swizzle (elements)

    const __bf16* Ab = A + (long long)b * sA;
    const __bf16* Bb = B + (long long)b * sB;

    f4 acc[FM][FN];
    #pragma unroll
    for (int i = 0; i < FM; i++)
        #pragma unroll
        for (int j = 0; j < FN; j++) acc[i][j] = (f4){0.f, 0.f, 0.f, 0.f};

    for (int kt = k0; kt < k1; kt += 64) {
        __syncthreads();                            // previous tile fully consumed
        #pragma unroll
        for (int i = 0; i < BM / 32; i++) {
            int ch = i * 4 + wid;
            gld_lds16(Ab + (long long)(m0 + ch * 8 + r_in) * lda + kt + csw,
                      As + ch * 512);
        }
        #pragma unroll
        for (int i = 0; i < BN / 32; i++) {
            int ch = i * 4 + wid;
            gld_lds16(Bb + (long long)(n0 + ch * 8 + r_in) * ldb + kt + csw,
                      Bs + ch * 512);
        }
        __syncthreads();                            // compiler drains vmcnt(0) here
        #pragma unroll
        for (int kk = 0; kk < 2; kk++) {
            bf16x8 af[FM], bfr[FN];
            #pragma unroll
            for (int i = 0; i < FM; i++)
                af[i] = *(const bf16x8*)&As[(wm + i * 16 + l16) * 64 + ((kk * 32 + l4 * 8) ^ rsw)];
            #pragma unroll
            for (int j = 0; j < FN; j++)
                bfr[j] = *(const bf16x8*)&Bs[(wn + j * 16 + l16) * 64 + ((kk * 32 + l4 * 8) ^ rsw)];
            #pragma unroll
            for (int i = 0; i < FM; i++)
                #pragma unroll
                for (int j = 0; j < FN; j++)
                    acc[i][j] = __builtin_amdgcn_mfma_f32_16x16x32_bf16(af[i], bfr[j], acc[i][j], 0, 0, 0);
        }
    }

    char* Dbase = (char*)D + (long long)b * sD * (D_F32 ? 4 : 2);
    if (ATOMIC) {
        float* D32 = (float*)Dbase;
        #pragma unroll
        for (int j = 0; j < FN; j++) {
            int col = n0 + wn + j * 16 + l16;
            #pragma unroll
            for (int i = 0; i < FM; i++)
                #pragma unroll
                for (int rr = 0; rr < 4; rr++) {
                    int row = m0 + wm + i * 16 + l4 * 4 + rr;
                    atomicAdd(D32 + (size_t)row * ldd + col, acc[i][j][rr]);
                }
        }
        return;
    }
    const float* t1b = t1 ? t1 + (long long)b * vt1 : nullptr;
    const float* t2b = t2 ? t2 + (long long)b * vt2 : nullptr;
    #pragma unroll
    for (int j = 0; j < FN; j++) {
        int col = n0 + wn + j * 16 + l16;
        float ct = t2b ? t2b[col] : 1.f;
        #pragma unroll
        for (int i = 0; i < FM; i++) {
            #pragma unroll
            for (int rr = 0; rr < 4; rr++) {
                int row = m0 + wm + i * 16 + l4 * 4 + rr;
                float val = acc[i][j][rr];
                if (t1b) val += tscale * t1b[row] * ct;
                size_t idx = (size_t)row * ldd + col;
                if (D_F32) ((float*)Dbase)[idx] = val;
                else       ((__bf16*)Dbase)[idx] = (__bf16)val;
            }
        }
    }
}

// ---------- generic batched GEMM (fallback paths + w13t) ----------
template<int BM, int BN, bool A_F32, bool B_F32, bool B_KMAJOR, bool D_F32, bool ATOMIC>
__global__ __launch_bounds__(256) void gemm_kernel(
    const void* __restrict__ Ap, const void* __restrict__ Bp, void* __restrict__ Dp,
    int K, int splitk, int lda, int ldb, int ldd,
    long long sA, long long sB, long long sD,
    const float* __restrict__ s1, int vs1, const float* __restrict__ s2, int vs2,
    const float* __restrict__ t1, int vt1, const float* __restrict__ t2, int vt2,
    float tscale)
{
    static_assert(B_KMAJOR || BN == 128, "NN staging assumes BN=128");
    constexpr int FM = BM / 32, FN = BN / 32;
    constexpr int LSA = 40;
    constexpr int LSB = B_KMAJOR ? 40 : 36;
    __shared__ __bf16 As[BM * LSA];
    __shared__ __bf16 Bs[BN * LSB];

    const int tid = threadIdx.x;
    const int b = blockIdx.z / splitk;
    const int chunk = blockIdx.z % splitk;
    const int klen = K / splitk;
    const int k0 = chunk * klen, k1 = k0 + klen;
    const int m0 = blockIdx.y * BM, n0 = blockIdx.x * BN;
    const int lane = tid & 63, wid = tid >> 6;
    const int wm = (wid >> 1) * (BM / 2), wn = (wid & 1) * (BN / 2);
    const int l16 = lane & 15, l4 = lane >> 4;

    const char* Abase = (const char*)Ap + (long long)b * sA * (A_F32 ? 4 : 2);
    const char* Bbase = (const char*)Bp + (long long)b * sB * (B_F32 ? 4 : 2);
    char* Dbase = (char*)Dp + (long long)b * sD * (D_F32 ? 4 : 2);

    f4 acc[FM][FN];
    #pragma unroll
    for (int i = 0; i < FM; i++)
        #pragma unroll
        for (int j = 0; j < FN; j++) acc[i][j] = (f4){0.f, 0.f, 0.f, 0.f};

    for (int kt = k0; kt < k1; kt += 32) {
        __syncthreads();
        if (A_F32) {
            const float* A32 = (const float*)Abase;
            #pragma unroll
            for (int it = 0; it < BM / 32; it++) {
                int q = it * 256 + tid;
                int r = q >> 3, c = (q & 7) * 4;
                f4 v = *(const f4*)(A32 + (size_t)(m0 + r) * lda + kt + c);
                bf16x4 o;
                o[0] = (__bf16)v[0]; o[1] = (__bf16)v[1]; o[2] = (__bf16)v[2]; o[3] = (__bf16)v[3];
                *(bf16x4*)&As[r * LSA + c] = o;
            }
        } else {
            const __bf16* A16 = (const __bf16*)Abase;
            #pragma unroll
            for (int it = 0; it < BM / 64; it++) {
                int q = it * 256 + tid;
                int r = q >> 2, c = (q & 3) * 8;
                *(bf16x8*)&As[r * LSA + c] = *(const bf16x8*)(A16 + (size_t)(m0 + r) * lda + kt + c);
            }
        }
        if (B_KMAJOR) {
            if (B_F32) {
                const float* B32 = (const float*)Bbase;
                #pragma unroll
                for (int it = 0; it < BN / 32; it++) {
                    int q = it * 256 + tid;
                    int r = q >> 3, c = (q & 7) * 4;
                    f4 v = *(const f4*)(B32 + (size_t)(n0 + r) * ldb + kt + c);
                    bf16x4 o;
                    o[0] = (__bf16)v[0]; o[1] = (__bf16)v[1]; o[2] = (__bf16)v[2]; o[3] = (__bf16)v[3];
                    *(bf16x4*)&Bs[r * LSB + c] = o;
                }
            } else {
                const __bf16* B16 = (const __bf16*)Bbase;
                #pragma unroll
                for (int it = 0; it < BN / 64; it++) {
                    int q = it * 256 + tid;
                    int r = q >> 2, c = (q & 3) * 8;
                    *(bf16x8*)&Bs[r * LSB + c] = *(const bf16x8*)(B16 + (size_t)(n0 + r) * ldb + kt + c);
                }
            }
        } else {
            const int n = tid & 127;
            const int kh = (tid >> 7) * 4;
            #pragma unroll
            for (int kk = 0; kk < 32; kk += 8) {
                int k = kk + kh;
                bf16x4 o;
                if (B_F32) {
                    const float* B32 = (const float*)Bbase;
                    #pragma unroll
                    for (int t = 0; t < 4; t++)
                        o[t] = (__bf16)B32[(size_t)(kt + k + t) * ldb + n0 + n];
                } else {
                    const __bf16* B16 = (const __bf16*)Bbase;
                    #pragma unroll
                    for (int t = 0; t < 4; t++)
                        o[t] = B16[(size_t)(kt + k + t) * ldb + n0 + n];
                }
                *(bf16x4*)&Bs[n * LSB + k] = o;
            }
        }
        __syncthreads();

        bf16x8 af[FM], bfr[FN];
        #pragma unroll
        for (int i = 0; i < FM; i++)
            af[i] = *(const bf16x8*)&As[(wm + i * 16 + l16) * LSA + l4 * 8];
        #pragma unroll
        for (int j = 0; j < FN; j++) {
            if (B_KMAJOR) {
                bfr[j] = *(const bf16x8*)&Bs[(wn + j * 16 + l16) * LSB + l4 * 8];
            } else {
                const __bf16* p = &Bs[(wn + j * 16 + l16) * LSB + l4 * 8];
                bf16x4 lo = *(const bf16x4*)p;
                bf16x4 hi = *(const bf16x4*)(p + 4);
                bf16x8 r;
                r[0]=lo[0]; r[1]=lo[1]; r[2]=lo[2]; r[3]=lo[3];
                r[4]=hi[0]; r[5]=hi[1]; r[6]=hi[2]; r[7]=hi[3];
                bfr[j] = r;
            }
        }
        #pragma unroll
        for (int i = 0; i < FM; i++)
            #pragma unroll
            for (int j = 0; j < FN; j++)
                acc[i][j] = __builtin_amdgcn_mfma_f32_16x16x32_bf16(af[i], bfr[j], acc[i][j], 0, 0, 0);
    }

    if (ATOMIC) {
        float* D32 = (float*)Dbase;
        #pragma unroll
        for (int j = 0; j < FN; j++) {
            int col = n0 + wn + j * 16 + l16;
            #pragma unroll
            for (int i = 0; i < FM; i++)
                #pragma unroll
                for (int rr = 0; rr < 4; rr++) {
                    int row = m0 + wm + i * 16 + l4 * 4 + rr;
                    atomicAdd(D32 + (size_t)row * ldd + col, acc[i][j][rr]);
                }
        }
        return;
    }
    const float* s1b = s1 ? s1 + (long long)b * vs1 : nullptr;
    const float* s2b = s2 ? s2 + (long long)b * vs2 : nullptr;
    const float* t1b = t1 ? t1 + (long long)b * vt1 : nullptr;
    const float* t2b = t2 ? t2 + (long long)b * vt2 : nullptr;
    #pragma unroll
    for (int j = 0; j < FN; j++) {
        int col = n0 + wn + j * 16 + l16;
        float cs = s2b ? s2b[col] : 1.f;
        float ct = t2b ? t2b[col] : 1.f;
        #pragma unroll
        for (int i = 0; i < FM; i++) {
            #pragma unroll
            for (int rr = 0; rr < 4; rr++) {
                int row = m0 + wm + i * 16 + l4 * 4 + rr;
                float val = acc[i][j][rr];
                if (s1b) val *= s1b[row];
                val *= cs;
                if (t1b) val += tscale * t1b[row] * ct;
                size_t idx = (size_t)row * ldd + col;
                if (D_F32) ((float*)Dbase)[idx] = val;
                else       ((__bf16*)Dbase)[idx] = (__bf16)val;
            }
        }
    }
}

extern "C" void kernel_launch(void* const* d_in, const int* in_sizes, int n_in,
                              void* d_out, int out_size, void* d_ws, size_t ws_size,
                              hipStream_t stream) {
    (void)in_sizes; (void)n_in; (void)out_size;
    const float* f_c = (const float*)d_in[0];
    const float* f_s = (const float*)d_in[1];
    const float* w1  = (const float*)d_in[2];
    const float* b1  = (const float*)d_in[3];
    const float* w2  = (const float*)d_in[4];
    const float* b2  = (const float*)d_in[5];
    const float* w3  = (const float*)d_in[6];
    const float* b3  = (const float*)d_in[7];
    float* out = (float*)d_out;

    char* ws = (char*)d_ws;
    float*  rstd_c = (float*)(ws + 0);
    float*  rmu_c  = (float*)(ws + 32768);
    float*  rstd_s = (float*)(ws + 65536);
    float*  rmu_s  = (float*)(ws + 98304);
    float*  vvec   = (float*)(ws + 131072);
    float*  qvec   = (float*)(ws + 163840);
    float*  u1     = (float*)(ws + 196608);
    float*  bw3    = (float*)(ws + 198656);
    float*  b1b3p  = (float*)(ws + 200704);
    __bf16* w2b    = (__bf16*)(ws + 262144);
    __bf16* w1t    = (__bf16*)(ws + 786432);
    __bf16* w3t    = (__bf16*)(ws + 1310720);
    __bf16* w13t   = (__bf16*)(ws + 1835008);
    float*  Graw   = (float*)(ws + 2359296);          // 16.8 MB, dead after gram_epi
    __bf16* Pt     = (__bf16*)(ws + 2359296);         // aliases Graw[0 : 8.4MB]
    __bf16* Mbuf   = (__bf16*)(ws + 10747904);        // aliases Graw[8.4 : 16.8MB]
    __bf16* G      = (__bf16*)(ws + 19136512);        // 8.4 MB -> core ends at 27.5 MB
    __bf16* fcb    = (__bf16*)(ws + 27525120);        // 67 MB, dead after Gram
    __bf16* fst    = (__bf16*)(ws + 27525120);        // aliases fcb (written post-Gram)
    __bf16* fsb    = (__bf16*)(ws + 94633984);        // 67 MB -> 161.7 MB
    const bool CONV = ws_size >= (size_t)161742848;

    const long long sBig = (long long)CCH * HW;
    const long long sSm  = (long long)CCH * CCH;

    stats_conv_kernel<<<dim3(BATCH * CCH), 256, 0, stream>>>(
        f_c, f_s, CONV ? fcb : nullptr, CONV ? fsb : nullptr,
        rstd_c, rmu_c, rstd_s, rmu_s);
    prep_w_kernel<<<dim3(1024, 3), 256, 0, stream>>>(w1, w2, w3, w1t, w2b, w3t);
    u_kernel<<<dim3(2, 2), 256, 0, stream>>>(w1, b3, w3, b1, u1, bw3);
    b1b3_kernel<<<1, 256, 0, stream>>>(b1, b3, b1b3p);
    (void)hipMemsetAsync(Graw, 0, (size_t)16777216, stream);

    // Gram (split-K=4, atomic fp32): Graw[b][c][d] = f_s[b,c,:].f_c[b,d,:]
    if (CONV)
        gemm_nt_lds<128, 128, true, true><<<dim3(4, 4, BATCH * 4), 256, 0, stream>>>(
            fsb, fcb, Graw, HW, 4, HW, HW, CCH, sBig, sBig, sSm,
            nullptr, 0, nullptr, 0, 0.f);
    else
        gemm_kernel<128,128,true,true,true,true,true><<<dim3(4, 4, BATCH * 4), 256, 0, stream>>>(
            f_s, f_c, Graw, HW, 4, HW, HW, CCH, sBig, sBig, sSm,
            nullptr,0, nullptr,0, nullptr,0, nullptr,0, 0.f);
    gram_epi_kernel<<<4096, 256, 0, stream>>>(Graw, G, rstd_s, rmu_s, rstd_c, rmu_c);

    // fst[b][n][e] = fsb[b][e][n]  (enables pure-NT final GEMM); fcb is dead now
    if (CONV)
        transpose_kernel<<<dim3(64, 8, BATCH), 256, 0, stream>>>(fsb, fst);

    // w13t[e][d] = sum_x w3[x,e]*w1[x,d]  (batch-independent, tiny)
    gemm_kernel<64,64,false,false,true,false,false><<<dim3(8, 8, 1), 256, 0, stream>>>(
        w3t, w1t, w13t, CCH, 1, CCH, CCH, CCH, 0, 0, 0,
        nullptr,0, nullptr,0, nullptr,0, nullptr,0, 0.f);
    // Pt[b][e][x] = sum_d w13t[e,d]*G[b][x,d]
    gemm_nt_lds<128, 128, false, false><<<dim3(4, 4, BATCH), 256, 0, stream>>>(
        w13t, G, Pt, CCH, 1, CCH, CCH, CCH, 0, sSm, sSm,
        nullptr, 0, nullptr, 0, 0.f);
    // M[b][c][e] = sum_x w2[c,x]*Pt[b][e,x] + 4096*b2[c]*bw3[e]
    gemm_nt_lds<128, 128, false, false><<<dim3(4, 4, BATCH), 256, 0, stream>>>(
        w2b, Pt, Mbuf, CCH, 1, CCH, CCH, CCH, 0, sSm, sSm,
        b2, 0, bw3, 0, 4096.f);

    q_kernel<<<BATCH * CCH, 64, 0, stream>>>(G, u1, qvec);
    v2_kernel<<<BATCH * CCH, 64, 0, stream>>>(w2, qvec, b2, b1b3p, vvec);

    // out[b][c][n] = sum_e M[b][c,e]*fst[b][n,e] + v[b][c]
    if (CONV)
        gemm_nt_lds<128, 128, true, false><<<dim3(32, 4, BATCH), 256, 0, stream>>>(
            Mbuf, fst, out, CCH, 1, CCH, CCH, HW, sSm, sBig, sBig,
            vvec, CCH, nullptr, 0, 1.f);
    else
        gemm_kernel<128,128,false,true,false,true,false><<<dim3(32, 4, BATCH), 256, 0, stream>>>(
            Mbuf, f_s, out, CCH, 1, CCH, HW, HW, sSm, sBig, sBig,
            nullptr,0, nullptr,0, vvec,CCH, nullptr,0, 1.f);
}

// Round 4
// 573.179 us; speedup vs baseline: 1.0947x; 1.0947x over previous
//
#include <hip/hip_runtime.h>
#include <hip/hip_bf16.h>

typedef float f4 __attribute__((ext_vector_type(4)));
typedef __bf16 bf16x4 __attribute__((ext_vector_type(4)));
typedef __bf16 bf16x8 __attribute__((ext_vector_type(8)));

#define BATCH 16
#define CCH 512
#define HW 4096

// async global->LDS, 16B per lane. LDS dest must be wave-uniform base (lane*16 implicit).
__device__ __forceinline__ void gld_lds16(const void* g, void* l) {
    __builtin_amdgcn_global_load_lds(
        (const __attribute__((address_space(1))) unsigned int*)g,
        (__attribute__((address_space(3))) unsigned int*)l, 16, 0, 0);
}

// ---------- fused stats + fp32->bf16 conversion for BOTH tensors (dst may be null) ----------
// Explicit 8-load preload: all 8 f4 loads issued before any arithmetic (MLP=8).
__global__ __launch_bounds__(256) void stats_conv_kernel(
    const float* __restrict__ fc, const float* __restrict__ fs,
    __bf16* __restrict__ fcb, __bf16* __restrict__ fsb,
    float* __restrict__ rstd_c, float* __restrict__ rmu_c,
    float* __restrict__ rstd_s, float* __restrict__ rmu_s)
{
    const int row = blockIdx.x;                    // B*C = 8192
    const int tid = threadIdx.x;
    const f4* pc4 = (const f4*)(fc + (size_t)row * HW);
    const f4* ps4 = (const f4*)(fs + (size_t)row * HW);
    f4 av[4], bv[4];
    av[0] = pc4[2 * tid];       av[1] = pc4[2 * tid + 1];
    av[2] = pc4[2 * tid + 512]; av[3] = pc4[2 * tid + 513];
    bv[0] = ps4[2 * tid];       bv[1] = ps4[2 * tid + 1];
    bv[2] = ps4[2 * tid + 512]; bv[3] = ps4[2 * tid + 513];
    float sc = 0.f, qc = 0.f, ssum = 0.f, qs = 0.f;
    #pragma unroll
    for (int u = 0; u < 4; u++)
        #pragma unroll
        for (int t = 0; t < 4; t++) {
            sc += av[u][t];  qc = fmaf(av[u][t], av[u][t], qc);
            ssum += bv[u][t]; qs = fmaf(bv[u][t], bv[u][t], qs);
        }
    if (fcb) {
        bf16x8 o0, o1, p0, p1;
        #pragma unroll
        for (int t = 0; t < 4; t++) {
            o0[t] = (__bf16)av[0][t]; o0[4 + t] = (__bf16)av[1][t];
            o1[t] = (__bf16)av[2][t]; o1[4 + t] = (__bf16)av[3][t];
            p0[t] = (__bf16)bv[0][t]; p0[4 + t] = (__bf16)bv[1][t];
            p1[t] = (__bf16)bv[2][t]; p1[4 + t] = (__bf16)bv[3][t];
        }
        *(bf16x8*)(fcb + (size_t)row * HW + 8 * tid)         = o0;
        *(bf16x8*)(fcb + (size_t)row * HW + 8 * (256 + tid)) = o1;
        *(bf16x8*)(fsb + (size_t)row * HW + 8 * tid)         = p0;
        *(bf16x8*)(fsb + (size_t)row * HW + 8 * (256 + tid)) = p1;
    }
    for (int off = 32; off > 0; off >>= 1) {
        sc   += __shfl_down(sc,   off, 64);
        qc   += __shfl_down(qc,   off, 64);
        ssum += __shfl_down(ssum, off, 64);
        qs   += __shfl_down(qs,   off, 64);
    }
    __shared__ float red[4][4];
    if ((tid & 63) == 0) {
        int w = tid >> 6;
        red[w][0] = sc; red[w][1] = qc; red[w][2] = ssum; red[w][3] = qs;
    }
    __syncthreads();
    if (tid == 0) {
        float Sc = red[0][0] + red[1][0] + red[2][0] + red[3][0];
        float Qc = red[0][1] + red[1][1] + red[2][1] + red[3][1];
        float Ss = red[0][2] + red[1][2] + red[2][2] + red[3][2];
        float Qs = red[0][3] + red[1][3] + red[2][3] + red[3][3];
        float muc = Sc * (1.f / HW), varc = Qc * (1.f / HW) - muc * muc;
        float mus = Ss * (1.f / HW), vars = Qs * (1.f / HW) - mus * mus;
        float rc = rsqrtf(varc + 1e-5f), rs = rsqrtf(vars + 1e-5f);
        rstd_c[row] = rc; rmu_c[row] = rc * muc;
        rstd_s[row] = rs; rmu_s[row] = rs * mus;
    }
}

// ---------- weight prep: w2 -> bf16; w1,w3 -> transposed bf16 ----------
__global__ __launch_bounds__(256) void prep_w_kernel(
    const float* __restrict__ w1, const float* __restrict__ w2, const float* __restrict__ w3,
    __bf16* __restrict__ w1t, __bf16* __restrict__ w2b, __bf16* __restrict__ w3t)
{
    int i = blockIdx.x * 256 + threadIdx.x;
    int z = blockIdx.y;
    if (z == 0)      w2b[i] = (__bf16)w2[i];
    else if (z == 1) w3t[i] = (__bf16)w3[(i & 511) * 512 + (i >> 9)];
    else             w1t[i] = (__bf16)w1[(i & 511) * 512 + (i >> 9)];
}

// ---------- u1[d] = sum_x w1[x,d]*b3[x] ; bw3[d] = sum_x w3[x,d]*b1[x] ----------
__global__ __launch_bounds__(256) void u_kernel(
    const float* __restrict__ w1, const float* __restrict__ b3,
    const float* __restrict__ w3, const float* __restrict__ b1,
    float* __restrict__ u1, float* __restrict__ bw3)
{
    int d = blockIdx.x * 256 + threadIdx.x;        // grid (2, 2)
    const float* W = blockIdx.y == 0 ? w1 : w3;
    const float* v = blockIdx.y == 0 ? b3 : b1;
    float* o       = blockIdx.y == 0 ? u1 : bw3;
    float s = 0.f;
    for (int x = 0; x < 512; x++) s += W[x * 512 + d] * v[x];
    o[d] = s;
}

__global__ __launch_bounds__(256) void b1b3_kernel(
    const float* __restrict__ b1, const float* __restrict__ b3, float* __restrict__ o)
{
    int t = threadIdx.x;
    float s = b1[t] * b3[t] + b1[t + 256] * b3[t + 256];
    for (int off = 32; off > 0; off >>= 1) s += __shfl_down(s, off, 64);
    __shared__ float ss[4];
    if ((t & 63) == 0) ss[t >> 6] = s;
    __syncthreads();
    if (t == 0) o[0] = ss[0] + ss[1] + ss[2] + ss[3];
}

// ---------- fused Gram epilogue + q: sums NP partials, scales -> G(bf16), q = G.u1 ----------
template<int NP>
__global__ __launch_bounds__(128) void gram_epi_q_kernel(
    const float* __restrict__ P0, const float* __restrict__ P1,
    const float* __restrict__ P2, const float* __restrict__ P3,
    __bf16* __restrict__ G, const float* __restrict__ u1,
    const float* __restrict__ rstd_s, const float* __restrict__ rmu_s,
    const float* __restrict__ rstd_c, const float* __restrict__ rmu_c,
    float* __restrict__ q)
{
    const int row = blockIdx.x;                    // b*512 + c
    const int b = row >> 9;
    const int t = threadIdx.x;                     // 128
    const int d0 = t * 4;
    const size_t flat = (size_t)row * 512 + d0;
    f4 g = *(const f4*)(P0 + flat);
    if (NP == 4) {
        g += *(const f4*)(P1 + flat);
        g += *(const f4*)(P2 + flat);
        g += *(const f4*)(P3 + flat);
    }
    const float rs = rstd_s[row], rm = rmu_s[row];
    const float* rc  = rstd_c + b * 512;
    const float* rmc = rmu_c  + b * 512;
    bf16x4 o;
    float qp = 0.f;
    #pragma unroll
    for (int k = 0; k < 4; k++) {
        float val = rs * rc[d0 + k] * g[k] - 4096.f * rm * rmc[d0 + k];
        o[k] = (__bf16)val;
        qp = fmaf((float)o[k], u1[d0 + k], qp);
    }
    *(bf16x4*)(G + flat) = o;
    for (int off = 32; off > 0; off >>= 1) qp += __shfl_down(qp, off, 64);
    __shared__ float sred[2];
    if ((t & 63) == 0) sred[t >> 6] = qp;
    __syncthreads();
    if (t == 0) q[row] = sred[0] + sred[1];
}

// ---------- old Gram epilogue (fallback path, atomic Graw) ----------
__global__ __launch_bounds__(256) void gram_epi_kernel(
    const float* __restrict__ Graw, __bf16* __restrict__ G,
    const float* __restrict__ rstd_s, const float* __restrict__ rmu_s,
    const float* __restrict__ rstd_c, const float* __restrict__ rmu_c)
{
    size_t i4 = (size_t)blockIdx.x * 256 + threadIdx.x;
    size_t flat = i4 * 4;
    int b  = (int)(flat >> 18);
    int c  = (int)((flat >> 9) & 511);
    int d0 = (int)(flat & 511);
    float rs = rstd_s[b * 512 + c], rm = rmu_s[b * 512 + c];
    f4 g = *(const f4*)(Graw + flat);
    bf16x4 o;
    #pragma unroll
    for (int t = 0; t < 4; t++) {
        float val = rs * rstd_c[b * 512 + d0 + t] * g[t]
                  - 4096.f * rm * rmu_c[b * 512 + d0 + t];
        o[t] = (__bf16)val;
    }
    *(bf16x4*)(G + flat) = o;
    (void)c;
}

// ---------- q[b,x] = sum_d G[b,x,d]*u1[d] (fallback path) ----------
__global__ __launch_bounds__(64) void q_kernel(
    const __bf16* __restrict__ G, const float* __restrict__ u1, float* __restrict__ q)
{
    int r = blockIdx.x;
    const __bf16* row = G + (size_t)r * 512;
    float s = 0.f;
    for (int i = threadIdx.x; i < 512; i += 64) s += (float)row[i] * u1[i];
    for (int off = 32; off > 0; off >>= 1) s += __shfl_down(s, off, 64);
    if (threadIdx.x == 0) q[r] = s;
}

// ---------- v[b,c] = sum_x w2[c,x]*q[b,x] + 4096*(b1.b3)*b2[c] ----------
__global__ __launch_bounds__(64) void v2_kernel(
    const float* __restrict__ w2, const float* __restrict__ qv,
    const float* __restrict__ b2, const float* __restrict__ b1b3,
    float* __restrict__ vv)
{
    int r = blockIdx.x, b = r >> 9, c = r & 511;
    float s = 0.f;
    for (int i = threadIdx.x; i < 512; i += 64) s += w2[c * 512 + i] * qv[b * 512 + i];
    for (int off = 32; off > 0; off >>= 1) s += __shfl_down(s, off, 64);
    if (threadIdx.x == 0) vv[r] = s + 4096.f * b1b3[0] * b2[c];
}

// ---------- bf16 transpose: out[b][n][e] = in[b][e][n]  (512 x 4096 -> 4096 x 512) ----------
__global__ __launch_bounds__(256) void transpose_kernel(
    const __bf16* __restrict__ in, __bf16* __restrict__ out)
{
    __shared__ __align__(16) __bf16 t[64 * 64];    // XOR slot-swizzled, pitch 64
    const int b = blockIdx.z, e0 = blockIdx.y * 64, n0 = blockIdx.x * 64;
    const int tid = threadIdx.x;
    const __bf16* src = in + ((size_t)b * 512 + e0) * HW + n0;
    __bf16* dst = out + ((size_t)b * HW + n0) * 512 + e0;
    #pragma unroll
    for (int it = 0; it < 2; it++) {
        int idx = it * 256 + tid;
        int e = idx >> 3, v = idx & 7;
        *(bf16x8*)&t[e * 64 + ((v ^ (e & 7)) * 8)] =
            *(const bf16x8*)(src + (size_t)e * HW + v * 8);
    }
    __syncthreads();
    #pragma unroll
    for (int it = 0; it < 2; it++) {
        int idx = it * 256 + tid;
        int n = idx >> 3, v = idx & 7;             // out row n, e-chunk v
        bf16x8 o;
        #pragma unroll
        for (int u = 0; u < 8; u++) {
            int row = v * 8 + u;                   // row&7 == u
            o[u] = t[row * 64 + (((n >> 3) ^ u) * 8) + (n & 7)];
        }
        *(bf16x8*)(dst + (size_t)n * 512 + v * 8) = o;
    }
}

// ---------- fast NT bf16 GEMM: global_load_lds staging, XOR-swizzled LDS ----------
// D[b][i][j] = sum_k A[b][i][k] * B[b][j][k]; BK=64, both operands K-major bf16.
// PARTIAL: split-K partials, chunk 0 -> D, chunk c>0 -> Dalt + (c-1)*altStride (fp32 stores).
// NTSTORE: nontemporal fp32 stores (single-use output).
// Epilogue (non-partial): val = acc + tscale*t1[row]*t2[col] (t1/t2 nullable).
template<int BM, int BN, bool D_F32, bool ATOMIC, bool PARTIAL, bool NTSTORE>
__global__ __launch_bounds__(256) void gemm_nt_lds(
    const __bf16* __restrict__ A, const __bf16* __restrict__ B, void* __restrict__ D,
    int K, int splitk, int lda, int ldb, int ldd,
    long long sA, long long sB, long long sD,
    const float* __restrict__ t1, int vt1, const float* __restrict__ t2, int vt2,
    float tscale, float* __restrict__ Dalt, long long altStride)
{
    constexpr int FM = BM / 32, FN = BN / 32;
    __shared__ __align__(16) __bf16 As[BM * 64];
    __shared__ __align__(16) __bf16 Bs[BN * 64];

    const int tid = threadIdx.x;
    const int lane = tid & 63, wid = tid >> 6;
    const int b = blockIdx.z / splitk, chunk = blockIdx.z % splitk;
    const int klen = K / splitk, k0 = chunk * klen, k1 = k0 + klen;
    const int m0 = blockIdx.y * BM, n0 = blockIdx.x * BN;
    const int l16 = lane & 15, l4 = lane >> 4;
    const int wm = (wid >> 1) * (BM / 2), wn = (wid & 1) * (BN / 2);
    // staging geometry: each 1024B chunk = 8 rows x 128B; 8 lanes/row, 16B/lane.
    const int r_in = lane >> 3, slot = lane & 7;
    const int csw = (slot ^ r_in) * 8;             // pre-swizzled source column (elements)
    const int rsw = (l16 & 7) * 8;                 // read-side swizzle (elements)

    const __bf16* Ab = A + (long long)b * sA;
    const __bf16* Bb = B + (long long)b * sB;

    f4 acc[FM][FN];
    #pragma unroll
    for (int i = 0; i < FM; i++)
        #pragma unroll
        for (int j = 0; j < FN; j++) acc[i][j] = (f4){0.f, 0.f, 0.f, 0.f};

    for (int kt = k0; kt < k1; kt += 64) {
        __syncthreads();                            // previous tile fully consumed
        #pragma unroll
        for (int i = 0; i < BM / 32; i++) {
            int ch = i * 4 + wid;
            gld_lds16(Ab + (long long)(m0 + ch * 8 + r_in) * lda + kt + csw,
                      As + ch * 512);
        }
        #pragma unroll
        for (int i = 0; i < BN / 32; i++) {
            int ch = i * 4 + wid;
            gld_lds16(Bb + (long long)(n0 + ch * 8 + r_in) * ldb + kt + csw,
                      Bs + ch * 512);
        }
        __syncthreads();                            // compiler drains vmcnt(0) here
        #pragma unroll
        for (int kk = 0; kk < 2; kk++) {
            bf16x8 af[FM], bfr[FN];
            #pragma unroll
            for (int i = 0; i < FM; i++)
                af[i] = *(const bf16x8*)&As[(wm + i * 16 + l16) * 64 + ((kk * 32 + l4 * 8) ^ rsw)];
            #pragma unroll
            for (int j = 0; j < FN; j++)
                bfr[j] = *(const bf16x8*)&Bs[(wn + j * 16 + l16) * 64 + ((kk * 32 + l4 * 8) ^ rsw)];
            #pragma unroll
            for (int i = 0; i < FM; i++)
                #pragma unroll
                for (int j = 0; j < FN; j++)
                    acc[i][j] = __builtin_amdgcn_mfma_f32_16x16x32_bf16(af[i], bfr[j], acc[i][j], 0, 0, 0);
        }
    }

    if (PARTIAL) {
        float* base = (chunk == 0) ? (float*)D : (Dalt + (long long)(chunk - 1) * altStride);
        base += (long long)b * sD;
        #pragma unroll
        for (int j = 0; j < FN; j++) {
            int col = n0 + wn + j * 16 + l16;
            #pragma unroll
            for (int i = 0; i < FM; i++)
                #pragma unroll
                for (int rr = 0; rr < 4; rr++) {
                    int row = m0 + wm + i * 16 + l4 * 4 + rr;
                    base[(size_t)row * ldd + col] = acc[i][j][rr];
                }
        }
        return;
    }
    char* Dbase = (char*)D + (long long)b * sD * (D_F32 ? 4 : 2);
    if (ATOMIC) {
        float* D32 = (float*)Dbase;
        #pragma unroll
        for (int j = 0; j < FN; j++) {
            int col = n0 + wn + j * 16 + l16;
            #pragma unroll
            for (int i = 0; i < FM; i++)
                #pragma unroll
                for (int rr = 0; rr < 4; rr++) {
                    int row = m0 + wm + i * 16 + l4 * 4 + rr;
                    atomicAdd(D32 + (size_t)row * ldd + col, acc[i][j][rr]);
                }
        }
        return;
    }
    const float* t1b = t1 ? t1 + (long long)b * vt1 : nullptr;
    const float* t2b = t2 ? t2 + (long long)b * vt2 : nullptr;
    #pragma unroll
    for (int j = 0; j < FN; j++) {
        int col = n0 + wn + j * 16 + l16;
        float ct = t2b ? t2b[col] : 1.f;
        #pragma unroll
        for (int i = 0; i < FM; i++) {
            #pragma unroll
            for (int rr = 0; rr < 4; rr++) {
                int row = m0 + wm + i * 16 + l4 * 4 + rr;
                float val = acc[i][j][rr];
                if (t1b) val += tscale * t1b[row] * ct;
                size_t idx = (size_t)row * ldd + col;
                if (D_F32) {
                    if (NTSTORE) __builtin_nontemporal_store(val, (float*)Dbase + idx);
                    else         ((float*)Dbase)[idx] = val;
                } else {
                    ((__bf16*)Dbase)[idx] = (__bf16)val;
                }
            }
        }
    }
}

// ---------- generic batched GEMM (fallback paths + w13t) ----------
template<int BM, int BN, bool A_F32, bool B_F32, bool B_KMAJOR, bool D_F32, bool ATOMIC>
__global__ __launch_bounds__(256) void gemm_kernel(
    const void* __restrict__ Ap, const void* __restrict__ Bp, void* __restrict__ Dp,
    int K, int splitk, int lda, int ldb, int ldd,
    long long sA, long long sB, long long sD,
    const float* __restrict__ s1, int vs1, const float* __restrict__ s2, int vs2,
    const float* __restrict__ t1, int vt1, const float* __restrict__ t2, int vt2,
    float tscale)
{
    static_assert(B_KMAJOR || BN == 128, "NN staging assumes BN=128");
    constexpr int FM = BM / 32, FN = BN / 32;
    constexpr int LSA = 40;
    constexpr int LSB = B_KMAJOR ? 40 : 36;
    __shared__ __bf16 As[BM * LSA];
    __shared__ __bf16 Bs[BN * LSB];

    const int tid = threadIdx.x;
    const int b = blockIdx.z / splitk;
    const int chunk = blockIdx.z % splitk;
    const int klen = K / splitk;
    const int k0 = chunk * klen, k1 = k0 + klen;
    const int m0 = blockIdx.y * BM, n0 = blockIdx.x * BN;
    const int lane = tid & 63, wid = tid >> 6;
    const int wm = (wid >> 1) * (BM / 2), wn = (wid & 1) * (BN / 2);
    const int l16 = lane & 15, l4 = lane >> 4;

    const char* Abase = (const char*)Ap + (long long)b * sA * (A_F32 ? 4 : 2);
    const char* Bbase = (const char*)Bp + (long long)b * sB * (B_F32 ? 4 : 2);
    char* Dbase = (char*)Dp + (long long)b * sD * (D_F32 ? 4 : 2);

    f4 acc[FM][FN];
    #pragma unroll
    for (int i = 0; i < FM; i++)
        #pragma unroll
        for (int j = 0; j < FN; j++) acc[i][j] = (f4){0.f, 0.f, 0.f, 0.f};

    for (int kt = k0; kt < k1; kt += 32) {
        __syncthreads();
        if (A_F32) {
            const float* A32 = (const float*)Abase;
            #pragma unroll
            for (int it = 0; it < BM / 32; it++) {
                int q = it * 256 + tid;
                int r = q >> 3, c = (q & 7) * 4;
                f4 v = *(const f4*)(A32 + (size_t)(m0 + r) * lda + kt + c);
                bf16x4 o;
                o[0] = (__bf16)v[0]; o[1] = (__bf16)v[1]; o[2] = (__bf16)v[2]; o[3] = (__bf16)v[3];
                *(bf16x4*)&As[r * LSA + c] = o;
            }
        } else {
            const __bf16* A16 = (const __bf16*)Abase;
            #pragma unroll
            for (int it = 0; it < BM / 64; it++) {
                int q = it * 256 + tid;
                int r = q >> 2, c = (q & 3) * 8;
                *(bf16x8*)&As[r * LSA + c] = *(const bf16x8*)(A16 + (size_t)(m0 + r) * lda + kt + c);
            }
        }
        if (B_KMAJOR) {
            if (B_F32) {
                const float* B32 = (const float*)Bbase;
                #pragma unroll
                for (int it = 0; it < BN / 32; it++) {
                    int q = it * 256 + tid;
                    int r = q >> 3, c = (q & 7) * 4;
                    f4 v = *(const f4*)(B32 + (size_t)(n0 + r) * ldb + kt + c);
                    bf16x4 o;
                    o[0] = (__bf16)v[0]; o[1] = (__bf16)v[1]; o[2] = (__bf16)v[2]; o[3] = (__bf16)v[3];
                    *(bf16x4*)&Bs[r * LSB + c] = o;
                }
            } else {
                const __bf16* B16 = (const __bf16*)Bbase;
                #pragma unroll
                for (int it = 0; it < BN / 64; it++) {
                    int q = it * 256 + tid;
                    int r = q >> 2, c = (q & 3) * 8;
                    *(bf16x8*)&Bs[r * LSB + c] = *(const bf16x8*)(B16 + (size_t)(n0 + r) * ldb + kt + c);
                }
            }
        } else {
            const int n = tid & 127;
            const int kh = (tid >> 7) * 4;
            #pragma unroll
            for (int kk = 0; kk < 32; kk += 8) {
                int k = kk + kh;
                bf16x4 o;
                if (B_F32) {
                    const float* B32 = (const float*)Bbase;
                    #pragma unroll
                    for (int t = 0; t < 4; t++)
                        o[t] = (__bf16)B32[(size_t)(kt + k + t) * ldb + n0 + n];
                } else {
                    const __bf16* B16 = (const __bf16*)Bbase;
                    #pragma unroll
                    for (int t = 0; t < 4; t++)
                        o[t] = B16[(size_t)(kt + k + t) * ldb + n0 + n];
                }
                *(bf16x4*)&Bs[n * LSB + k] = o;
            }
        }
        __syncthreads();

        bf16x8 af[FM], bfr[FN];
        #pragma unroll
        for (int i = 0; i < FM; i++)
            af[i] = *(const bf16x8*)&As[(wm + i * 16 + l16) * LSA + l4 * 8];
        #pragma unroll
        for (int j = 0; j < FN; j++) {
            if (B_KMAJOR) {
                bfr[j] = *(const bf16x8*)&Bs[(wn + j * 16 + l16) * LSB + l4 * 8];
            } else {
                const __bf16* p = &Bs[(wn + j * 16 + l16) * LSB + l4 * 8];
                bf16x4 lo = *(const bf16x4*)p;
                bf16x4 hi = *(const bf16x4*)(p + 4);
                bf16x8 r;
                r[0]=lo[0]; r[1]=lo[1]; r[2]=lo[2]; r[3]=lo[3];
                r[4]=hi[0]; r[5]=hi[1]; r[6]=hi[2]; r[7]=hi[3];
                bfr[j] = r;
            }
        }
        #pragma unroll
        for (int i = 0; i < FM; i++)
            #pragma unroll
            for (int j = 0; j < FN; j++)
                acc[i][j] = __builtin_amdgcn_mfma_f32_16x16x32_bf16(af[i], bfr[j], acc[i][j], 0, 0, 0);
    }

    if (ATOMIC) {
        float* D32 = (float*)Dbase;
        #pragma unroll
        for (int j = 0; j < FN; j++) {
            int col = n0 + wn + j * 16 + l16;
            #pragma unroll
            for (int i = 0; i < FM; i++)
                #pragma unroll
                for (int rr = 0; rr < 4; rr++) {
                    int row = m0 + wm + i * 16 + l4 * 4 + rr;
                    atomicAdd(D32 + (size_t)row * ldd + col, acc[i][j][rr]);
                }
        }
        return;
    }
    const float* s1b = s1 ? s1 + (long long)b * vs1 : nullptr;
    const float* s2b = s2 ? s2 + (long long)b * vs2 : nullptr;
    const float* t1b = t1 ? t1 + (long long)b * vt1 : nullptr;
    const float* t2b = t2 ? t2 + (long long)b * vt2 : nullptr;
    #pragma unroll
    for (int j = 0; j < FN; j++) {
        int col = n0 + wn + j * 16 + l16;
        float cs = s2b ? s2b[col] : 1.f;
        float ct = t2b ? t2b[col] : 1.f;
        #pragma unroll
        for (int i = 0; i < FM; i++) {
            #pragma unroll
            for (int rr = 0; rr < 4; rr++) {
                int row = m0 + wm + i * 16 + l4 * 4 + rr;
                float val = acc[i][j][rr];
                if (s1b) val *= s1b[row];
                val *= cs;
                if (t1b) val += tscale * t1b[row] * ct;
                size_t idx = (size_t)row * ldd + col;
                if (D_F32) ((float*)Dbase)[idx] = val;
                else       ((__bf16*)Dbase)[idx] = (__bf16)val;
            }
        }
    }
}

extern "C" void kernel_launch(void* const* d_in, const int* in_sizes, int n_in,
                              void* d_out, int out_size, void* d_ws, size_t ws_size,
                              hipStream_t stream) {
    (void)in_sizes; (void)n_in; (void)out_size;
    const float* f_c = (const float*)d_in[0];
    const float* f_s = (const float*)d_in[1];
    const float* w1  = (const float*)d_in[2];
    const float* b1  = (const float*)d_in[3];
    const float* w2  = (const float*)d_in[4];
    const float* b2  = (const float*)d_in[5];
    const float* w3  = (const float*)d_in[6];
    const float* b3  = (const float*)d_in[7];
    float* out = (float*)d_out;

    char* ws = (char*)d_ws;
    float*  rstd_c = (float*)(ws + 0);
    float*  rmu_c  = (float*)(ws + 32768);
    float*  rstd_s = (float*)(ws + 65536);
    float*  rmu_s  = (float*)(ws + 98304);
    float*  vvec   = (float*)(ws + 131072);
    float*  qvec   = (float*)(ws + 163840);
    float*  u1     = (float*)(ws + 196608);
    float*  bw3    = (float*)(ws + 198656);
    float*  b1b3p  = (float*)(ws + 200704);
    __bf16* w2b    = (__bf16*)(ws + 262144);
    __bf16* w1t    = (__bf16*)(ws + 786432);
    __bf16* w3t    = (__bf16*)(ws + 1310720);
    __bf16* w13t   = (__bf16*)(ws + 1835008);
    float*  Graw   = (float*)(ws + 2359296);          // 16.8 MB (partial 0; dead after epi)
    __bf16* Pt     = (__bf16*)(ws + 2359296);         // aliases Graw[0 : 8.4MB]
    __bf16* Mbuf   = (__bf16*)(ws + 10747904);        // aliases Graw[8.4 : 16.8MB]
    __bf16* G      = (__bf16*)(ws + 19136512);        // 8.4 MB -> core ends at 27.5 MB
    __bf16* fcb    = (__bf16*)(ws + 27525120);        // 67 MB, dead after Gram
    __bf16* fst    = (__bf16*)(ws + 27525120);        // aliases fcb (written post-Gram)
    __bf16* fsb    = (__bf16*)(ws + 94633984);        // 67 MB -> 161.7 MB
    float*  slab   = (float*)(ws + 161742848);        // 3x16.8 MB split-K partials (if room)
    const bool CONV  = ws_size >= (size_t)161742848;
    const bool BIGWS = ws_size >= (size_t)161742848 + (size_t)3 * 16777216;

    const long long sBig = (long long)CCH * HW;
    const long long sSm  = (long long)CCH * CCH;
    const long long sPart = (long long)BATCH * CCH * CCH;   // floats per partial slab

    stats_conv_kernel<<<dim3(BATCH * CCH), 256, 0, stream>>>(
        f_c, f_s, CONV ? fcb : nullptr, CONV ? fsb : nullptr,
        rstd_c, rmu_c, rstd_s, rmu_s);
    prep_w_kernel<<<dim3(1024, 3), 256, 0, stream>>>(w1, w2, w3, w1t, w2b, w3t);
    u_kernel<<<dim3(2, 2), 256, 0, stream>>>(w1, b3, w3, b1, u1, bw3);
    b1b3_kernel<<<1, 256, 0, stream>>>(b1, b3, b1b3p);

    if (CONV && BIGWS) {
        // Gram split-K=4, NO atomics: partial 0 -> Graw, partials 1..3 -> ws slabs.
        gemm_nt_lds<128, 128, true, false, true, false><<<dim3(4, 4, BATCH * 4), 256, 0, stream>>>(
            fsb, fcb, Graw, HW, 4, HW, HW, CCH, sBig, sBig, sSm,
            nullptr, 0, nullptr, 0, 0.f, slab, sPart);
        gram_epi_q_kernel<4><<<BATCH * CCH, 128, 0, stream>>>(
            Graw, slab, slab + sPart, slab + 2 * sPart,
            G, u1, rstd_s, rmu_s, rstd_c, rmu_c, qvec);
    } else if (CONV) {
        // round-1-proven atomic Gram; fused epilogue+q still applies (single buffer).
        (void)hipMemsetAsync(Graw, 0, (size_t)16777216, stream);
        gemm_nt_lds<128, 128, true, true, false, false><<<dim3(4, 4, BATCH * 4), 256, 0, stream>>>(
            fsb, fcb, Graw, HW, 4, HW, HW, CCH, sBig, sBig, sSm,
            nullptr, 0, nullptr, 0, 0.f, nullptr, 0);
        gram_epi_q_kernel<1><<<BATCH * CCH, 128, 0, stream>>>(
            Graw, nullptr, nullptr, nullptr,
            G, u1, rstd_s, rmu_s, rstd_c, rmu_c, qvec);
    } else {
        (void)hipMemsetAsync(Graw, 0, (size_t)16777216, stream);
        gemm_kernel<128,128,true,true,true,true,true><<<dim3(4, 4, BATCH * 4), 256, 0, stream>>>(
            f_s, f_c, Graw, HW, 4, HW, HW, CCH, sBig, sBig, sSm,
            nullptr,0, nullptr,0, nullptr,0, nullptr,0, 0.f);
        gram_epi_kernel<<<4096, 256, 0, stream>>>(Graw, G, rstd_s, rmu_s, rstd_c, rmu_c);
        q_kernel<<<BATCH * CCH, 64, 0, stream>>>(G, u1, qvec);
    }

    // fst[b][n][e] = fsb[b][e][n]  (enables pure-NT final GEMM); fcb is dead now
    if (CONV)
        transpose_kernel<<<dim3(64, 8, BATCH), 256, 0, stream>>>(fsb, fst);

    // w13t[e][d] = sum_x w3[x,e]*w1[x,d]  (batch-independent, tiny)
    gemm_kernel<64,64,false,false,true,false,false><<<dim3(8, 8, 1), 256, 0, stream>>>(
        w3t, w1t, w13t, CCH, 1, CCH, CCH, CCH, 0, 0, 0,
        nullptr,0, nullptr,0, nullptr,0, nullptr,0, 0.f);
    // Pt[b][e][x] = sum_d w13t[e,d]*G[b][x,d]   (64^2 tiles: 1024 blocks, 4/CU)
    gemm_nt_lds<64, 64, false, false, false, false><<<dim3(8, 8, BATCH), 256, 0, stream>>>(
        w13t, G, Pt, CCH, 1, CCH, CCH, CCH, 0, sSm, sSm,
        nullptr, 0, nullptr, 0, 0.f, nullptr, 0);
    // M[b][c][e] = sum_x w2[c,x]*Pt[b][e,x] + 4096*b2[c]*bw3[e]
    gemm_nt_lds<64, 64, false, false, false, false><<<dim3(8, 8, BATCH), 256, 0, stream>>>(
        w2b, Pt, Mbuf, CCH, 1, CCH, CCH, CCH, 0, sSm, sSm,
        b2, 0, bw3, 0, 4096.f, nullptr, 0);

    v2_kernel<<<BATCH * CCH, 64, 0, stream>>>(w2, qvec, b2, b1b3p, vvec);

    // out[b][c][n] = sum_e M[b][c,e]*fst[b][n,e] + v[b][c]  (nontemporal stores)
    if (CONV)
        gemm_nt_lds<128, 128, true, false, false, true><<<dim3(32, 4, BATCH), 256, 0, stream>>>(
            Mbuf, fst, out, CCH, 1, CCH, CCH, HW, sSm, sBig, sBig,
            vvec, CCH, nullptr, 0, 1.f, nullptr, 0);
    else
        gemm_kernel<128,128,false,true,false,true,false><<<dim3(32, 4, BATCH), 256, 0, stream>>>(
            Mbuf, f_s, out, CCH, 1, CCH, HW, HW, sSm, sBig, sBig,
            nullptr,0, nullptr,0, vvec,CCH, nullptr,0, 1.f);
}